// Round 7
// baseline (188.976 us; speedup 1.0000x reference)
//
#include <hip/hip_runtime.h>
#include <cstdint>

constexpr int BTOT = 1048576;
constexpr int LCLS = 81;
constexpr int GRP  = 9;
constexpr int RPB  = 256;                  // rows per block (single wave)
constexpr int NBLK = BTOT / RPB;           // 4096 blocks
constexpr int FPB  = RPB * LCLS;           // 20736 floats per block (20736 % 9 == 0)
constexpr int GPB  = RPB * GRP;            // 2304 groups per block
constexpr float FIX = 67108864.0f;         // 2^26 fixed-point loss scale

__device__ __forceinline__ float readlane_f(float v, int l) {
    return __int_as_float(__builtin_amdgcn_readlane(__float_as_int(v), l));
}

// Rare knife-edge path (~1e-5 of rows): group argmax in f64 from global row.
__device__ __attribute__((noinline)) int refine_group_f64(const float* __restrict__ xrow)
{
    double best = -1.0; int bi = 0;
    #pragma unroll
    for (int g = 0; g < GRP; ++g) {
        double s = 0.0;
        #pragma unroll
        for (int j = 0; j < GRP; ++j) s += exp((double)xrow[g * GRP + j]);
        if (s > best) { best = s; bi = g; }
    }
    return bi;
}

struct LaneState { int m, g, le, lr, r, kbase; };

// Process one 256-float chunk (lane owns 4 consecutive floats).
// Groups of 9 floats span <=3 consecutive lanes; head lane (group's first
// float) gathers neighbor segments via shfl_down; groups spilling into the
// next chunk (lanes 62/63) complete via readlane peek of next chunk lanes 0/1.
__device__ __forceinline__ void proc_chunk(
    const float4 cv, const float4 nv, const int lane, LaneState& st,
    float* gs, unsigned char* gpos, const unsigned short* tl, float* etx)
{
    const float v0 = cv.x, v1 = cv.y, v2 = cv.z, v3 = cv.w;
    const float e0 = __expf(v0), e1 = __expf(v1), e2 = __expf(v2), e3 = __expf(v3);
    const int m = st.m, g = st.g, le = st.le, lr = st.lr, r = st.r;
    const int s = 9 - m;                       // own floats in group g (1..4 capped)

    // segment A: floats in group g, positions m+i (scan ascending, strict > = first-win)
    float sA = e0;  float xmA = v0;  int xpA = m;
    if (s > 1) { sA += e1; if (v1 > xmA) { xmA = v1; xpA = m + 1; } }
    if (s > 2) { sA += e2; if (v2 > xmA) { xmA = v2; xpA = m + 2; } }
    if (s > 3) { sA += e3; if (v3 > xmA) { xmA = v3; xpA = m + 3; } }
    // segment B: floats in group g+1 (exists iff m>=6), positions i-s
    float sB = 0.0f; float xmB = -1e30f; int xpB = 0;
    if (s <= 1) { sB += e1; if (v1 > xmB) { xmB = v1; xpB = 1 - s; } }
    if (s <= 2) { sB += e2; if (v2 > xmB) { xmB = v2; xpB = 2 - s; } }
    if (s <= 3) { sB += e3; if (v3 > xmB) { xmB = v3; xpB = 3 - s; } }

    const float sA1  = __shfl_down(sA, 1),  sA2  = __shfl_down(sA, 2);
    const float xmA1 = __shfl_down(xmA, 1), xmA2 = __shfl_down(xmA, 2);
    const int   xpA1 = __shfl_down(xpA, 1), xpA2 = __shfl_down(xpA, 2);

    // capture exp(x[target]) when a lane's float index equals the row's target
    {
        const int tA = (int)tl[r];
        const int r1 = (r < RPB - 1) ? r + 1 : r;
        const int tB = (int)tl[r1];
        if (le + 0 == tA) etx[r] = e0;
        const bool x1 = (lr + 1 >= LCLS); if (le + 1 == (x1 ? tB : tA)) etx[x1 ? r + 1 : r] = e1;
        const bool x2 = (lr + 2 >= LCLS); if (le + 2 == (x2 ? tB : tA)) etx[x2 ? r + 1 : r] = e2;
        const bool x3 = (lr + 3 >= LCLS); if (le + 3 == (x3 ? tB : tA)) etx[x3 ? r + 1 : r] = e3;
    }

    const bool headA = (m == 0), headB = (m >= 6);
    if (headA || headB) {
        const int G  = headA ? g : (g + 1);
        float tot    = headA ? sA  : sB;
        float tm     = headA ? xmA : xmB;
        int   tp     = headA ? xpA : xpB;
        if (lane < 62) {
            tot += sA1 + sA2;
            if (xmA1 > tm) { tm = xmA1; tp = xpA1; }
            if (xmA2 > tm) { tm = xmA2; tp = xpA2; }
        } else {
            if (lane == 62) {                      // lane 63's whole f4 is in G here
                tot += sA1;
                if (xmA1 > tm) { tm = xmA1; tp = xpA1; }
            }
            const int Ln  = st.kbase + 256;        // next chunk's first local idx
            const int cnt = 9 * G + 9 - Ln;        // group floats spilling into next chunk (1..8)
            const int p0  = 9 - cnt;
            const float n0 = readlane_f(nv.x, 0), n1 = readlane_f(nv.y, 0),
                        n2 = readlane_f(nv.z, 0), n3 = readlane_f(nv.w, 0),
                        n4 = readlane_f(nv.x, 1), n5 = readlane_f(nv.y, 1),
                        n6 = readlane_f(nv.z, 1), n7 = readlane_f(nv.w, 1);
            if (cnt > 0) { tot += __expf(n0); if (n0 > tm) { tm = n0; tp = p0;     } }
            if (cnt > 1) { tot += __expf(n1); if (n1 > tm) { tm = n1; tp = p0 + 1; } }
            if (cnt > 2) { tot += __expf(n2); if (n2 > tm) { tm = n2; tp = p0 + 2; } }
            if (cnt > 3) { tot += __expf(n3); if (n3 > tm) { tm = n3; tp = p0 + 3; } }
            if (cnt > 4) { tot += __expf(n4); if (n4 > tm) { tm = n4; tp = p0 + 4; } }
            if (cnt > 5) { tot += __expf(n5); if (n5 > tm) { tm = n5; tp = p0 + 5; } }
            if (cnt > 6) { tot += __expf(n6); if (n6 > tm) { tm = n6; tp = p0 + 6; } }
            if (cnt > 7) { tot += __expf(n7); if (n7 > tm) { tm = n7; tp = p0 + 7; } }
        }
        gs[G]   = tot;
        gpos[G] = (unsigned char)tp;
    }

    // advance by 256 floats: 256 = 9*28+4 = 81*3+13
    st.m  = (m + 4 >= 9)   ? (m - 5)   : (m + 4);
    st.g  = g + 28 + ((m + 4 >= 9) ? 1 : 0);
    st.lr = (lr + 13 >= 81) ? (lr - 68) : (lr + 13);
    st.r  = r + 3 + ((lr + 13 >= 81) ? 1 : 0);
    st.le = le + 256;
    st.kbase += 256;
}

__global__ __launch_bounds__(64) void hl_main(
    const float* __restrict__ x, const int* __restrict__ tgt,
    float* __restrict__ out, unsigned long long* __restrict__ part)
{
    __shared__ float          gs[GPB];      // 9216 B: group exp-sums
    __shared__ float          etx[RPB];     // 1024 B: exp(x[target]) per row
    __shared__ unsigned short tl[RPB];      //  512 B: 81*r + target[r]
    __shared__ unsigned char  gpos[GPB];    // 2304 B: within-group argmax pos
                                            // total 13056 B -> 12 blocks/CU

    const int lane = threadIdx.x;
    const int bid  = blockIdx.x;
    const float* xb = x + (size_t)bid * FPB;

    // targets first (their wait retires nothing else), then chunk prefetch
    #pragma unroll
    for (int q = 0; q < 4; ++q) {
        const int rr = q * 64 + lane;
        const int tv = tgt[bid * RPB + rr];
        tl[rr] = (unsigned short)(rr * LCLS + tv);
    }

    const float4* pw = reinterpret_cast<const float4*>(xb) + lane;
    float4 c0 = pw[0 * 64], c1 = pw[1 * 64], c2 = pw[2 * 64];

    LaneState st;
    st.le = 4 * lane; st.m = st.le % 9; st.g = st.le / 9;
    st.lr = st.le % 81; st.r = st.le / 81; st.kbase = 0;

    #pragma unroll 1
    for (int it = 0; it < 27; ++it) {          // 81 chunks, 3-deep rotation
        const int k = it * 3;
        proc_chunk(c0, c1, lane, st, gs, gpos, tl, etx);
        if (k + 3 <= 80) c0 = pw[(k + 3) * 64];
        proc_chunk(c1, c2, lane, st, gs, gpos, tl, etx);
        if (k + 4 <= 80) c1 = pw[(k + 4) * 64];
        proc_chunk(c2, c0, lane, st, gs, gpos, tl, etx);   // k==80: peek unused (no 62/63 heads)
        if (k + 5 <= 80) c2 = pw[(k + 5) * 64];
    }

    // ---- phase 2: one row per lane, 4 passes, all from the small LDS ----
    unsigned long long lq = 0;
    unsigned dT = 0;
    #pragma unroll
    for (int p = 0; p < 4; ++p) {
        const int r2 = p * 64 + lane;
        float gsr[GRP];
        #pragma unroll
        for (int j = 0; j < GRP; ++j) gsr[j] = gs[r2 * GRP + j];
        float S = gsr[0];
        #pragma unroll
        for (int j = 1; j < GRP; ++j) S += gsr[j];

        float g1 = gsr[0], g2 = -1e30f; int gi = 0;
        #pragma unroll
        for (int j = 1; j < GRP; ++j) {
            const float v = gsr[j];
            const bool gt2 = v > g1;
            g2 = gt2 ? g1 : (v > g2 ? v : g2);
            g1 = gt2 ? v : g1;
            gi = gt2 ? j : gi;
        }

        const int t = (int)tl[r2] - LCLS * r2;
        const int parent = t / GRP;
        float gpar = gsr[0];
        #pragma unroll
        for (int j = 1; j < GRP; ++j) gpar = (parent == j) ? gsr[j] : gpar;

        if (g1 - g2 < 1e-5f * g1)
            gi = refine_group_f64(xb + (size_t)r2 * LCLS);

        const int wi = (int)gpos[r2 * GRP + gi];   // exact raw-x argmax within group
        const int pred = gi * GRP + wi;

        const float et  = etx[r2];
        const float win = 0.5f * (gpar + et) / S;
        const float nl  = -logf(win);
        lq += (unsigned long long)llrintf(nl * FIX);
        dT += (pred == t) ? 0u : ((gi == parent) ? 1u : 2u);

        out[1 + bid * RPB + r2] = (float)pred;
    }

    // ---- deterministic single-wave reduction ----
    #pragma unroll
    for (int off = 32; off > 0; off >>= 1) {
        lq += __shfl_down(lq, off);
        dT += __shfl_down(dT, off);
    }
    if (lane == 0) {
        part[bid] = lq;
        part[NBLK + bid] = (unsigned long long)dT;
    }
}

__global__ __launch_bounds__(1024) void hl_final(
    const unsigned long long* __restrict__ part, float* __restrict__ out)
{
    const int tid = threadIdx.x;
    unsigned long long a = 0, b = 0;
    for (int i = tid; i < NBLK; i += 1024) { a += part[i]; b += part[NBLK + i]; }
    #pragma unroll
    for (int off = 32; off > 0; off >>= 1) { a += __shfl_down(a, off); b += __shfl_down(b, off); }
    __shared__ unsigned long long rA[16], rB[16];
    if ((tid & 63) == 0) { rA[tid >> 6] = a; rB[tid >> 6] = b; }
    __syncthreads();
    if (tid == 0) {
        unsigned long long ta = 0, tb = 0;
        #pragma unroll
        for (int w = 0; w < 16; ++w) { ta += rA[w]; tb += rB[w]; }
        const double loss = ((double)ta / 67108864.0) / (double)BTOT;
        out[0] = (float)loss;                  // -mean(log(win))
        out[1 + BTOT] = (float)tb;             // total_dist
    }
}

extern "C" void kernel_launch(void* const* d_in, const int* in_sizes, int n_in,
                              void* d_out, int out_size, void* d_ws, size_t ws_size,
                              hipStream_t stream) {
    const float* outputs = (const float*)d_in[0];
    const int*   target  = (const int*)d_in[1];
    float* out = (float*)d_out;
    unsigned long long* part = (unsigned long long*)d_ws;   // needs 2*4096*8 = 65,536 B

    hl_main<<<NBLK, 64, 0, stream>>>(outputs, target, out, part);
    hl_final<<<1, 1024, 0, stream>>>(part, out);
}